// Round 12
// baseline (21.546 us; speedup 1.0000x reference)
//
#include <hip/hip_runtime.h>
#include <math.h>

#define DD       768
#define HDIM     512
#define TOKDIM   256
#define LOCALDIM 16384
#define FEATDIM  16640            // 16384 + 256
#define BB       64
#define THRESH   0.7f
#define ONEF     0x3f800000u      // bit pattern of 1.0f
#define UC       8                // unit chunks of 64
#define UNITS    64
#define BPG      2                // batches per group; 32 bgroups x 8 uc = 256 blocks

// NetVLAD local branch is identically 1.0 (softmax(axis=1).sum(axis=1) == 1),
// so feats = [inv * ones(16384), g/norm], norm = sqrt(16384 + ||g||^2), and
// sim_ij = (16384 + g_i.g_j) * inv_i * inv_j.

// ---- K_A: 256 blocks = 32 batch-pairs x 8 unit-chunks. Full-d layer-1 for
// 64 units (in-block fold + bias + ReLU) then layer-2 partial g for those
// units. Per-block reads: 192 KB W1-slice (x2 batches) + 64 KB W2-slice.
__global__ __launch_bounds__(1024) void kA(
    const float* __restrict__ gtok, const float* __restrict__ W1,
    const float* __restrict__ b1,   const float* __restrict__ W2,
    float* __restrict__ pg,         unsigned* __restrict__ maskU)
{
    __shared__ float  xs[BPG][DD];     // 6 KB
    __shared__ float4 buf[2112];       // 33.8 KB: hh[64][33] f4, then gg[16][129] f4
    __shared__ float  pr[1024];        // 4 KB fold stage
    __shared__ float  hs[BPG][UNITS];  // post-ReLU h slice
    const int blk = blockIdx.x, t = threadIdx.x;
    const int bg = blk >> 3, uc = blk & 7;
    const int b0 = bg * BPG, u0 = uc * UNITS;

    if (blk == 0) {                    // zero mask; graph edge orders before kB
        maskU[t] = 0u; maskU[t+1024] = 0u; maskU[t+2048] = 0u; maskU[t+3072] = 0u;
    }
    for (int i = t; i < BPG * DD; i += 1024)
        xs[i / DD][i % DD] = gtok[(size_t)(b0 + i / DD) * DD + (i % DD)];
    __syncthreads();

    // layer 1: thread = (u4 = t&15 -> 4 units, q = t>>4 -> 12-d slice), 2 batches
    {
        const int u4 = t & 15, q = t >> 4, d0 = q * 12;
        const float4* w = (const float4*)W1 + (size_t)d0 * 128 + uc * 16 + u4;
        float4 a0 = {0,0,0,0}, a1 = {0,0,0,0};
        #pragma unroll
        for (int d = 0; d < 12; ++d) {
            const float4 wv = w[(size_t)d * 128];
            const float x0 = xs[0][d0+d], x1 = xs[1][d0+d];
            a0.x = fmaf(x0, wv.x, a0.x); a0.y = fmaf(x0, wv.y, a0.y);
            a0.z = fmaf(x0, wv.z, a0.z); a0.w = fmaf(x0, wv.w, a0.w);
            a1.x = fmaf(x1, wv.x, a1.x); a1.y = fmaf(x1, wv.y, a1.y);
            a1.z = fmaf(x1, wv.z, a1.z); a1.w = fmaf(x1, wv.w, a1.w);
        }
        buf[q * 33 + u4 * 2 + 0] = a0;     // hh[q][u4*2+bb], pad stride 33
        buf[q * 33 + u4 * 2 + 1] = a1;
    }
    __syncthreads();
    {   // fold 64 q -> 8 (col c = u4*8 + bb*4 + comp; float stride 132)
        const float* hf = (const float*)buf;
        const int c = t & 127, qg = t >> 7;
        float s = 0.f;
        #pragma unroll
        for (int qq = 0; qq < 8; ++qq) s += hf[(size_t)(qg*8+qq)*132 + c];
        pr[qg * 128 + c] = s;
    }
    __syncthreads();
    if (t < 128) {                     // c=t -> u = (c>>3)*4 + (c&3), bb = (c>>2)&1
        const int u = ((t >> 3) << 2) | (t & 3), bb = (t >> 2) & 1;
        float s = b1[u0 + u];
        #pragma unroll
        for (int qg = 0; qg < 8; ++qg) s += pr[qg * 128 + t];
        hs[bb][u] = fmaxf(s, 0.f);
    }
    __syncthreads();

    // layer 2 partial: thread = (o4 = t&63 -> 4 outs, jq = t>>6 -> 4 units)
    {
        const int o4 = t & 63, jq = t >> 6;
        const float4* w = (const float4*)W2 + (size_t)(u0 + jq * 4) * 64 + o4;
        float4 a0 = {0,0,0,0}, a1 = {0,0,0,0};
        #pragma unroll
        for (int jj = 0; jj < 4; ++jj) {
            const float4 wv = w[(size_t)jj * 64];
            const float h0 = hs[0][jq*4+jj], h1 = hs[1][jq*4+jj];
            a0.x = fmaf(h0, wv.x, a0.x); a0.y = fmaf(h0, wv.y, a0.y);
            a0.z = fmaf(h0, wv.z, a0.z); a0.w = fmaf(h0, wv.w, a0.w);
            a1.x = fmaf(h1, wv.x, a1.x); a1.y = fmaf(h1, wv.y, a1.y);
            a1.z = fmaf(h1, wv.z, a1.z); a1.w = fmaf(h1, wv.w, a1.w);
        }
        buf[jq * 129 + o4 * 2 + 0] = a0;   // gg[jq][o4*2+bb], pad stride 129
        buf[jq * 129 + o4 * 2 + 1] = a1;
    }
    __syncthreads();
    {   // fold 16 jq -> 2 (col c = o4*8 + bb*4 + comp; float stride 516)
        const float* gf = (const float*)buf;
        const int c = t & 511, qg = t >> 9;
        float s = 0.f;
        #pragma unroll
        for (int qq = 0; qq < 8; ++qq) s += gf[(size_t)(qg*8+qq)*516 + c];
        pr[qg * 512 + c] = s;
    }
    __syncthreads();
    if (t < 512) {                     // no b2 here (added once in kB)
        const int o = ((t >> 3) << 2) | (t & 3), bb = (t >> 2) & 1;
        pg[((size_t)uc * BB + b0 + bb) * TOKDIM + o] = pr[t] + pr[512 + t];
    }
}

// ---- K_B: 64 blocks. Block i: reduce pg (8 chunks, 512 KB, L2/MALL-hot) into
// gT, all inv-norms, feats row i (fill + gn), sim row i, top-k, mask ORs. ----
__global__ __launch_bounds__(1024) void kB(
    const float* __restrict__ pg, const float* __restrict__ b2,
    const int* __restrict__ kptr, float* __restrict__ feats,
    unsigned* __restrict__ maskU)
{
    __shared__ float gT[TOKDIM][BB + 1];   // stride 65: conflict-free both ways
    __shared__ float part[16][BB];
    __shared__ float invs[BB];
    const int i = blockIdx.x, t = threadIdx.x;
    const float4* pg4 = (const float4*)pg;
    const float4* b24 = (const float4*)b2;

    #pragma unroll
    for (int r = 0; r < 4; ++r) {          // f indexes [64 j][64 d4] float4
        const int f = r * 1024 + t, j = f >> 6, d4 = f & 63;
        float4 v = b24[d4];
        #pragma unroll
        for (int u = 0; u < UC; ++u) {
            const float4 p = pg4[(size_t)u * 4096 + f];
            v.x += p.x; v.y += p.y; v.z += p.z; v.w += p.w;
        }
        gT[d4*4+0][j] = v.x; gT[d4*4+1][j] = v.y;
        gT[d4*4+2][j] = v.z; gT[d4*4+3][j] = v.w;
    }
    __syncthreads();

    {   // ||g_j||^2 partials
        const int q = t >> 6, j = t & 63;
        float s = 0.f;
        #pragma unroll
        for (int dd = 0; dd < 16; ++dd) { const float v = gT[q*16+dd][j]; s = fmaf(v, v, s); }
        part[q][j] = s;
    }
    __syncthreads();
    if (t < BB) {
        float ssq = 0.f;
        #pragma unroll
        for (int q = 0; q < 16; ++q) ssq += part[q][t];
        invs[t] = 1.f / fmaxf(sqrtf((float)LOCALDIM + ssq), 1e-12f);
    }
    __syncthreads();
    const float inv = invs[i];

    // feats row i: 16384-wide inv fill + normalized g
    {
        float4* f4 = (float4*)(feats + (size_t)i * FEATDIM);
        const float4 v = make_float4(inv, inv, inv, inv);
        f4[t] = v; f4[t + 1024] = v; f4[t + 2048] = v; f4[t + 3072] = v;
        if (t < TOKDIM) feats[(size_t)i * FEATDIM + LOCALDIM + t] = gT[t][i] * inv;
    }
    __syncthreads();

    {   // sim row i partials: gT[d][i] broadcast x gT[d][j] conflict-free
        const int q = t >> 6, j = t & 63;
        float s = 0.f;
        #pragma unroll
        for (int dd = 0; dd < 16; ++dd)
            s = fmaf(gT[q*16+dd][i], gT[q*16+dd][j], s);
        part[q][j] = s;
    }
    __syncthreads();
    if (t < BB) {                          // wave 0: full 64-lane wave
        float dot = 0.f;
        #pragma unroll
        for (int q = 0; q < 16; ++q) dot += part[q][t];
        const float sv = ((float)LOCALDIM + dot) * inv * invs[t];
        int k = *kptr; if (k > BB) k = BB;
        float v = sv;
        unsigned long long rowbits = 0;
        for (int p = 0; p < k; ++p) {      // ties -> lowest index (jax top_k)
            float m = v;
            #pragma unroll
            for (int off = 32; off > 0; off >>= 1) m = fmaxf(m, __shfl_xor(m, off));
            const unsigned long long ball = __ballot(v == m);
            const int bi = __ffsll(ball) - 1;
            rowbits |= 1ull << bi;
            if (t == bi) v = -INFINITY;
            if (t == 0) atomicOr(&maskU[bi * BB + i], ONEF);   // mask[idx, row] = 1
        }
        const unsigned base =
            ((sv > THRESH) || (t == i) || ((rowbits >> t) & 1ull)) ? ONEF : 0u;
        if (base) atomicOr(&maskU[i * BB + t], base);          // row i
    }
}

extern "C" void kernel_launch(void* const* d_in, const int* in_sizes, int n_in,
                              void* d_out, int out_size, void* d_ws, size_t ws_size,
                              hipStream_t stream) {
    const float* gtok = (const float*)d_in[1];
    const float* W1g  = (const float*)d_in[6];
    const float* b1g  = (const float*)d_in[7];
    const float* W2g  = (const float*)d_in[8];
    const float* b2g  = (const float*)d_in[9];
    const int*   kp   = (const int*)d_in[10];

    float*    feats = (float*)d_out;                              // [64, 16640]
    unsigned* maskU = (unsigned*)(feats + (size_t)BB * FEATDIM);  // [64,64] as bits
    float*    pg    = (float*)d_ws;                               // [8][64][256]

    hipLaunchKernelGGL(kA, dim3(256), dim3(1024), 0, stream,
                       gtok, W1g, b1g, W2g, pg, maskU);
    hipLaunchKernelGGL(kB, dim3(BB),  dim3(1024), 0, stream,
                       pg, b2g, kp, feats, maskU);
}